// Round 12
// baseline (128.374 us; speedup 1.0000x reference)
//
#include <hip/hip_runtime.h>
#include <hip/hip_bf16.h>
#include <math.h>

// Block-sparse local+strided causal attention, MI355X (gfx950). Round 12.
// prep (R10 verified): K,V fp32 -> block-contiguous XOR-swizzled bf16 tiles;
//   V uses 4x4 register micro-transpose.
// attn: 1024 WGs x 256 thr (4 waves x 16 q-rows). SOFTWARE-PIPELINED across
//   k-tiles: iteration t does softmax(t) -> P-write(t) -> QK(t+1) -> P-read(t)
//   -> PV(t), so the P LDS round-trip latency is covered by the independent
//   QK MFMAs of the next tile. K staged through a 3-slot LDS ring (24 KB,
//   global_load_lds, prefetch depth 2); V B-frags direct from the L2-resident
//   swizzled global tile (R11-verified), issued at iteration top. Static-max
//   softmax (exp2 domain), v_exp_f32, trunc P->bf16.

#define NHEADS 16
#define HDIM   64
#define NBLK   64
#define SEQLEN 4096
#define KP     72     // prep scratch pitch (shorts)
#define SMAX   16.0f  // static softmax max (exp2 domain)

typedef __attribute__((ext_vector_type(8))) short bf16x8;
typedef __attribute__((ext_vector_type(4))) float f32x4;

__device__ __forceinline__ short f2bf(float x) {
    union { float f; unsigned u; } c; c.f = x;
    unsigned u = c.u;
    return (short)((u + 0x7FFFu + ((u >> 16) & 1u)) >> 16); // RNE fp32->bf16
}
__device__ __forceinline__ short f2bf_trunc(float x) {
    union { float f; unsigned u; } c; c.f = x;
    return (short)(c.u >> 16);  // truncate; fine for P in (0, ~2^-7]
}

__device__ __forceinline__ void load_lds16(const short* g, const short* l) {
    __builtin_amdgcn_global_load_lds(
        (const __attribute__((address_space(1))) void*)g,
        (__attribute__((address_space(3))) void*)l, 16, 0, 0);
}

// ---------------- prep: one WG per (h, jb) --------------------------------
__global__ __launch_bounds__(256)
void prep_kernel(const float* __restrict__ k, const float* __restrict__ v,
                 short* __restrict__ kt, short* __restrict__ vt) {
    __shared__ short tile[64 * KP];     // V^T [d][key]
    const int b = blockIdx.x;           // b = h*64 + jb
    const int h = b >> 6, jb = b & 63;
    const int tid = threadIdx.x;

    // V: 4x4 micro-tile register transpose -> 4 b64 LDS writes
    {
        const int kg = tid >> 4;        // keys 4kg..4kg+3
        const int dg = tid & 15;        // d    4dg..4dg+3
        float4 f[4];
        #pragma unroll
        for (int j = 0; j < 4; ++j)
            f[j] = *(const float4*)(v + ((size_t)(jb * 64 + 4 * kg + j) * NHEADS + h) * HDIM + 4 * dg);
        #pragma unroll
        for (int i = 0; i < 4; ++i) {
            short4 s4;
            s4.x = f2bf(((const float*)&f[0])[i]);
            s4.y = f2bf(((const float*)&f[1])[i]);
            s4.z = f2bf(((const float*)&f[2])[i]);
            s4.w = f2bf(((const float*)&f[3])[i]);
            *(short4*)&tile[(4 * dg + i) * KP + 4 * kg] = s4;  // tile_T[d][key]
        }
    }
    __syncthreads();
    short* vtile = vt + (size_t)b * 4096;
    #pragma unroll
    for (int ii = 0; ii < 2; ++ii) {
        int idx = ii * 256 + tid;       // destination group index G
        int d = idx >> 3, gsw = idx & 7;
        int g = gsw ^ (d & 7);
        bf16x8 val = *(const bf16x8*)&tile[d * KP + g * 8];
        *(bf16x8*)(vtile + (size_t)idx * 8) = val;
    }
    short* ktile = kt + (size_t)b * 4096;
    #pragma unroll
    for (int ii = 0; ii < 2; ++ii) {
        int idx = ii * 256 + tid;       // source (row, g)
        int r = idx >> 3, g = idx & 7;
        const float* src = k + ((size_t)(jb * 64 + r) * NHEADS + h) * HDIM + g * 8;
        float4 f0 = *(const float4*)src;
        float4 f1 = *(const float4*)(src + 4);
        bf16x8 a;
        a[0]=f2bf(f0.x); a[1]=f2bf(f0.y); a[2]=f2bf(f0.z); a[3]=f2bf(f0.w);
        a[4]=f2bf(f1.x); a[5]=f2bf(f1.y); a[6]=f2bf(f1.z); a[7]=f2bf(f1.w);
        int G = r * 8 + (g ^ (r & 7));
        *(bf16x8*)(ktile + (size_t)G * 8) = a;
    }
}

// -- attention: 1024 WGs, 4 waves x 16 rows, pipelined QK(t+1) over P(t) ----
__global__ __launch_bounds__(256, 4)
void attn_kernel(const short* __restrict__ kt, const short* __restrict__ vt,
                 const float* __restrict__ q, float* __restrict__ out) {
    __shared__ short kl[3 * 4096];      // 3-slot K ring (8 KB/slot)
    __shared__ short pl[4 * 1024];      // per-wave P scratch: 16 x 64, swizzled

    const int b    = blockIdx.x;        // 1024 WGs: b = g6(6) | hl(1) | xcd(3)
    const int h    = ((b & 7) << 1) | ((b >> 3) & 1);   // 2 heads per XCD
    const int g6   = b >> 4;
    const int qi   = (g6 & 1) ? (63 - (g6 >> 1)) : (g6 >> 1);  // heavy/light mix
    const int tid  = threadIdx.x;
    const int wave = tid >> 6;          // 0..3
    const int lane = tid & 63;
    const int l16  = lane & 15;
    const int quad = lane >> 4;
    const int row0 = qi * 64 + wave * 16;
    short* pw = pl + wave * 1024;

    // ---- Q A-fragments (A[m=l16][k=quad*8+j]) ----
    const float* qrow = q + ((size_t)(row0 + l16) * NHEADS + h) * HDIM;
    bf16x8 a_q[2];
    #pragma unroll
    for (int kk = 0; kk < 2; ++kk) {
        const float* src = qrow + kk * 32 + quad * 8;
        float4 f0 = *(const float4*)(src);
        float4 f1 = *(const float4*)(src + 4);
        bf16x8 a;
        a[0]=f2bf(f0.x); a[1]=f2bf(f0.y); a[2]=f2bf(f0.z); a[3]=f2bf(f0.w);
        a[4]=f2bf(f1.x); a[5]=f2bf(f1.y); a[6]=f2bf(f1.z); a[7]=f2bf(f1.w);
        a_q[kk] = a;
    }

    f32x4 o[4];
    float lsum[4];
    #pragma unroll
    for (int nt = 0; nt < 4; ++nt) { o[nt] = (f32x4){0.f,0.f,0.f,0.f}; lsum[nt] = 0.f; }

    const short* kth = kt + (size_t)(h * 64) * 4096;
    const short* vth = vt + (size_t)(h * 64) * 4096;
    const float kscale = 0.125f * 1.4426950408889634f;

    // closed-form iterator: verticals (j ≡ 7-h mod 8, j < loc), then locals
    const int j0  = (7 - h) & 7;
    const int loc = (qi > 7) ? (qi - 7) : 0;
    const int nv  = (j0 < loc) ? ((loc - j0 + 7) >> 3) : 0;
    const int T   = nv + (qi - loc + 1);
#define JB(u) (((u) < nv) ? (j0 + 8 * (u)) : (loc + ((u) - nv)))

    const int sbase = wave * 64;        // K staging groups for this wave
    const int r7    = l16 & 7;
    const int gk0   = (quad ^ r7) * 8;  // K/V-frag swizzled group offset (shorts)
    const int gk1   = gk0 ^ 32;
    const int rowb  = l16 * 64;
    // V direct-global fragment offsets (shorts, within a 4096-short tile)
    int vo[4][2];
    #pragma unroll
    for (int nt = 0; nt < 4; ++nt) {
        vo[nt][0] = (nt * 16 + l16) * 64 + gk0;
        vo[nt][1] = (nt * 16 + l16) * 64 + gk1;
    }
    // P-read b128 offsets (swizzle consistent with P-write below)
    const int pr0   = rowb + ((quad ^ r7) << 3);
    const int pr1   = rowb + (((4 + quad) ^ r7) << 3);

    // ---- prologue: stage K(0)->slot0, K(1)->slot1; compute S(0) ----
    {
        const short* k0 = kth + (size_t)JB(0) * 4096;
        load_lds16(k0 + (size_t)(sbase + lane) * 8,       &kl[sbase * 8]);
        load_lds16(k0 + (size_t)(256 + sbase + lane) * 8, &kl[(256 + sbase) * 8]);
        if (1 < T) {
            const short* k1 = kth + (size_t)JB(1) * 4096;
            load_lds16(k1 + (size_t)(sbase + lane) * 8,       &kl[4096 + sbase * 8]);
            load_lds16(k1 + (size_t)(256 + sbase + lane) * 8, &kl[4096 + (256 + sbase) * 8]);
        }
    }
    __syncthreads();   // K(0), K(1) staged and visible

    f32x4 s_cur[4], s_next[4];
    #pragma unroll
    for (int nt = 0; nt < 4; ++nt) {
        bf16x8 k0 = *(const bf16x8*)&kl[nt * 1024 + rowb + gk0];
        bf16x8 k1 = *(const bf16x8*)&kl[nt * 1024 + rowb + gk1];
        s_cur[nt] = (f32x4){0.f,0.f,0.f,0.f};
        s_cur[nt] = __builtin_amdgcn_mfma_f32_16x16x32_bf16(a_q[0], k0, s_cur[nt], 0, 0, 0);
        s_cur[nt] = __builtin_amdgcn_mfma_f32_16x16x32_bf16(a_q[1], k1, s_cur[nt], 0, 0, 0);
    }

    for (int t = 0; t < T; ++t) {
        const int jb = JB(t);

        __syncthreads();   // slot (t+2)%3 free; staging of K(t+1) drained

        // ---- prefetch K(t+2) into ring slot (t+2)%3 (after barrier) ----
        if (t + 2 < T) {
            const int so = ((t + 2) % 3) * 4096;
            const short* kn = kth + (size_t)JB(t + 2) * 4096;
            load_lds16(kn + (size_t)(sbase + lane) * 8,       &kl[so + sbase * 8]);
            load_lds16(kn + (size_t)(256 + sbase + lane) * 8, &kl[so + (256 + sbase) * 8]);
        }

        // ---- issue V(t) B-frag loads from global (L2-resident tile) ----
        const short* vtb = vth + (size_t)jb * 4096;
        bf16x8 vf[4][2];
        #pragma unroll
        for (int nt = 0; nt < 4; ++nt) {
            vf[nt][0] = *(const bf16x8*)(vtb + vo[nt][0]);
            vf[nt][1] = *(const bf16x8*)(vtb + vo[nt][1]);
        }

        // ---- softmax(t) on s_cur + swizzled P write ----
        const bool diag = (jb == qi);
        #pragma unroll
        for (int nt = 0; nt < 4; ++nt) {
            const int gw = nt * 2 + (l16 >> 3);   // key group = key>>3
            const int ow = l16 & 7;               // key offset in group
            #pragma unroll
            for (int r = 0; r < 4; ++r) {
                float raw = s_cur[nt][r];
                if (diag) {
                    int n = nt * 16 + l16;
                    int mrow = wave * 16 + quad * 4 + r;
                    if (n > mrow) raw = -INFINITY;
                }
                float pv = __builtin_amdgcn_exp2f(fmaf(raw, kscale, -SMAX));
                lsum[r] += pv;
                const int prow = quad * 4 + r;
                pw[prow * 64 + ((gw ^ (prow & 7)) << 3) + ow] = f2bf_trunc(pv);
            }
        }

        // ---- QK(t+1): independent MFMAs cover the P write->read latency ----
        if (t + 1 < T) {
            const short* kb = &kl[((t + 1) % 3) * 4096];
            #pragma unroll
            for (int nt = 0; nt < 4; ++nt) {
                bf16x8 k0 = *(const bf16x8*)&kb[nt * 1024 + rowb + gk0];
                bf16x8 k1 = *(const bf16x8*)&kb[nt * 1024 + rowb + gk1];
                s_next[nt] = (f32x4){0.f,0.f,0.f,0.f};
                s_next[nt] = __builtin_amdgcn_mfma_f32_16x16x32_bf16(a_q[0], k0, s_next[nt], 0, 0, 0);
                s_next[nt] = __builtin_amdgcn_mfma_f32_16x16x32_bf16(a_q[1], k1, s_next[nt], 0, 0, 0);
            }
        }

        // ---- P A-frags (wave-private; lgkm wait only on own writes) ----
        bf16x8 a_p0 = *(const bf16x8*)&pw[pr0];
        bf16x8 a_p1 = *(const bf16x8*)&pw[pr1];

        // ---- O += P V ----
        #pragma unroll
        for (int nt = 0; nt < 4; ++nt) {
            o[nt] = __builtin_amdgcn_mfma_f32_16x16x32_bf16(a_p0, vf[nt][0], o[nt], 0, 0, 0);
            o[nt] = __builtin_amdgcn_mfma_f32_16x16x32_bf16(a_p1, vf[nt][1], o[nt], 0, 0, 0);
        }

        #pragma unroll
        for (int nt = 0; nt < 4; ++nt) s_cur[nt] = s_next[nt];
    }

    // ---- final l reduction + epilogue ----
    #pragma unroll
    for (int r = 0; r < 4; ++r) {
        float tsum = lsum[r];
        #pragma unroll
        for (int off = 1; off < 16; off <<= 1)
            tsum += __shfl_xor(tsum, off);
        float inv = 1.0f / tsum;
        int trow = row0 + quad * 4 + r;
        float* orow = out + ((size_t)trow * NHEADS + h) * HDIM;
        #pragma unroll
        for (int nt = 0; nt < 4; ++nt)
            orow[nt * 16 + l16] = o[nt][r] * inv;
    }
#undef JB
}

extern "C" void kernel_launch(void* const* d_in, const int* in_sizes, int n_in,
                              void* d_out, int out_size, void* d_ws, size_t ws_size,
                              hipStream_t stream) {
    const float* q = (const float*)d_in[0];
    const float* k = (const float*)d_in[1];
    const float* v = (const float*)d_in[2];
    float* out = (float*)d_out;

    const size_t tileBytes = (size_t)NHEADS * NBLK * 4096 * sizeof(short); // 8 MiB each
    short* kt = (short*)d_ws;
    short* vt = (short*)((char*)d_ws + tileBytes);
    prep_kernel<<<dim3(NHEADS * NBLK), dim3(256), 0, stream>>>(k, v, kt, vt);
    attn_kernel<<<dim3(NHEADS * NBLK), dim3(256), 0, stream>>>(kt, vt, q, out);
}

// Round 13
// 119.528 us; speedup vs baseline: 1.0740x; 1.0740x over previous
//
#include <hip/hip_runtime.h>
#include <hip/hip_bf16.h>
#include <math.h>

// Block-sparse local+strided causal attention, MI355X (gfx950). Round 13.
// Consolidation: best-measured attn (R8: 512 WGs x 512 thr, q-block pair,
// dbuf prefetch-after-barrier global_load_lds staging, swizzled P scratch)
// + R10 prep (4x4 register micro-transpose for V).
// prep: K,V fp32 -> block-contiguous XOR-swizzled bf16 tiles.
//   ktile[h][jb]: 512 x 16B groups, G = row*8 + (g ^ (row&7)), K[row][g*8..+8]
//   vtile[h][jb]: same swizzle on V^T[d][key].

#define NHEADS 16
#define HDIM   64
#define NBLK   64
#define SEQLEN 4096
#define KP     72     // prep scratch pitch (shorts)
#define SMAX   16.0f  // static softmax max (exp2 domain)

typedef __attribute__((ext_vector_type(8))) short bf16x8;
typedef __attribute__((ext_vector_type(4))) float f32x4;

__device__ __forceinline__ short f2bf(float x) {
    union { float f; unsigned u; } c; c.f = x;
    unsigned u = c.u;
    return (short)((u + 0x7FFFu + ((u >> 16) & 1u)) >> 16); // RNE fp32->bf16
}
__device__ __forceinline__ short f2bf_trunc(float x) {
    union { float f; unsigned u; } c; c.f = x;
    return (short)(c.u >> 16);  // truncate; fine for P in (0, ~2^-7]
}

__device__ __forceinline__ void load_lds16(const short* g, const short* l) {
    __builtin_amdgcn_global_load_lds(
        (const __attribute__((address_space(1))) void*)g,
        (__attribute__((address_space(3))) void*)l, 16, 0, 0);
}

// ---------------- prep: one WG per (h, jb) --------------------------------
__global__ __launch_bounds__(256)
void prep_kernel(const float* __restrict__ k, const float* __restrict__ v,
                 short* __restrict__ kt, short* __restrict__ vt) {
    __shared__ short tile[64 * KP];     // V^T [d][key]
    const int b = blockIdx.x;           // b = h*64 + jb
    const int h = b >> 6, jb = b & 63;
    const int tid = threadIdx.x;

    // V: 4x4 micro-tile register transpose -> 4 b64 LDS writes
    {
        const int kg = tid >> 4;        // keys 4kg..4kg+3
        const int dg = tid & 15;        // d    4dg..4dg+3
        float4 f[4];
        #pragma unroll
        for (int j = 0; j < 4; ++j)
            f[j] = *(const float4*)(v + ((size_t)(jb * 64 + 4 * kg + j) * NHEADS + h) * HDIM + 4 * dg);
        #pragma unroll
        for (int i = 0; i < 4; ++i) {
            short4 s4;
            s4.x = f2bf(((const float*)&f[0])[i]);
            s4.y = f2bf(((const float*)&f[1])[i]);
            s4.z = f2bf(((const float*)&f[2])[i]);
            s4.w = f2bf(((const float*)&f[3])[i]);
            *(short4*)&tile[(4 * dg + i) * KP + 4 * kg] = s4;  // tile_T[d][key]
        }
    }
    __syncthreads();
    short* vtile = vt + (size_t)b * 4096;
    #pragma unroll
    for (int ii = 0; ii < 2; ++ii) {
        int idx = ii * 256 + tid;       // destination group index G
        int d = idx >> 3, gsw = idx & 7;
        int g = gsw ^ (d & 7);
        bf16x8 val = *(const bf16x8*)&tile[d * KP + g * 8];
        *(bf16x8*)(vtile + (size_t)idx * 8) = val;
    }
    short* ktile = kt + (size_t)b * 4096;
    #pragma unroll
    for (int ii = 0; ii < 2; ++ii) {
        int idx = ii * 256 + tid;       // source (row, g)
        int r = idx >> 3, g = idx & 7;
        const float* src = k + ((size_t)(jb * 64 + r) * NHEADS + h) * HDIM + g * 8;
        float4 f0 = *(const float4*)src;
        float4 f1 = *(const float4*)(src + 4);
        bf16x8 a;
        a[0]=f2bf(f0.x); a[1]=f2bf(f0.y); a[2]=f2bf(f0.z); a[3]=f2bf(f0.w);
        a[4]=f2bf(f1.x); a[5]=f2bf(f1.y); a[6]=f2bf(f1.z); a[7]=f2bf(f1.w);
        int G = r * 8 + (g ^ (r & 7));
        *(bf16x8*)(ktile + (size_t)G * 8) = a;
    }
}

// ------- attention: 8 waves x 16 rows, q-block pair, dbuf staging ----------
__global__ __launch_bounds__(512, 4)
void attn_kernel(const short* __restrict__ kt, const short* __restrict__ vt,
                 const float* __restrict__ q, float* __restrict__ out) {
    __shared__ short kv[2 * 8192];      // dbuf: [K tile 4096 | V tile 4096] x2
    __shared__ short pl[8 * 1024];      // per-wave P scratch: 16 x 64, swizzled

    const int b    = blockIdx.x;        // 512 WGs
    const int h    = ((b & 7) << 1) | ((b >> 3) & 1);   // 2 heads per XCD
    const int g5   = b >> 4;            // 0..31
    const int m    = (g5 < 16) ? g5 : (47 - g5);        // b,b+256 -> (m,31-m)
    const int q0   = 2 * m, q1 = 2 * m + 1;
    const int tid  = threadIdx.x;
    const int wave = tid >> 6;          // 0..7
    const int lane = tid & 63;
    const int l16  = lane & 15;
    const int quad = lane >> 4;

    const int myqi   = q0 + (wave >> 2);
    const int stripe = wave & 3;
    const int row0   = myqi * 64 + stripe * 16;
    short* pw = pl + wave * 1024;

    // ---- Q A-fragments (A[m=l16][k=quad*8+j]) ----
    const float* qrow = q + ((size_t)(row0 + l16) * NHEADS + h) * HDIM;
    bf16x8 a_q[2];
    #pragma unroll
    for (int kk = 0; kk < 2; ++kk) {
        const float* src = qrow + kk * 32 + quad * 8;
        float4 f0 = *(const float4*)(src);
        float4 f1 = *(const float4*)(src + 4);
        bf16x8 a;
        a[0]=f2bf(f0.x); a[1]=f2bf(f0.y); a[2]=f2bf(f0.z); a[3]=f2bf(f0.w);
        a[4]=f2bf(f1.x); a[5]=f2bf(f1.y); a[6]=f2bf(f1.z); a[7]=f2bf(f1.w);
        a_q[kk] = a;
    }

    f32x4 o[4];
    float lsum[4];
    #pragma unroll
    for (int nt = 0; nt < 4; ++nt) { o[nt] = (f32x4){0.f,0.f,0.f,0.f}; lsum[nt] = 0.f; }

    const short* kth = kt + (size_t)(h * 64) * 4096;
    const short* vth = vt + (size_t)(h * 64) * 4096;
    const float kscale = 0.125f * 1.4426950408889634f;

    // union iterator over the pair: verticals (j ≡ 7-h mod 8, j < l0), then
    // locals [l0 .. q1], l0 = max(0, q0-7)
    const int j0  = (7 - h) & 7;
    const int l0  = (q0 > 7) ? (q0 - 7) : 0;
    const int nv  = (j0 < l0) ? ((l0 - j0 + 7) >> 3) : 0;
    const int T   = nv + (q1 - l0 + 1);

    const int r7   = l16 & 7;
    const int gk0  = (quad ^ r7) * 8;   // K/V-frag swizzled group offset (shorts)
    const int gk1  = gk0 ^ 32;
    const int rowb = l16 * 64;
    // P-read b128 offsets (swizzle consistent with the P-write below)
    const int pr0  = rowb + ((quad ^ r7) << 3);
    const int pr1  = rowb + (((4 + quad) ^ r7) << 3);

    // stage tile 0 into buf 0: thread tid covers group tid of each tile
    {
        const short* ktb = kth + (size_t)((0 < nv) ? j0 : l0) * 4096;
        const short* vtb = vth + (size_t)((0 < nv) ? j0 : l0) * 4096;
        load_lds16(ktb + (size_t)tid * 8, &kv[wave * 512]);
        load_lds16(vtb + (size_t)tid * 8, &kv[4096 + wave * 512]);
    }

    for (int t = 0; t < T; ++t) {
        const int jb = (t < nv) ? (j0 + 8 * t) : (l0 + (t - nv));

        __syncthreads();   // drains staging of tile t (issued a full iter ago)

        // ---- prefetch tile t+1 into the other buffer (after the barrier) ----
        if (t + 1 < T) {
            const int jn = (t + 1 < nv) ? (j0 + 8 * (t + 1)) : (l0 + (t + 1 - nv));
            const int bo = ((t + 1) & 1) * 8192;
            const short* ktb = kth + (size_t)jn * 4096;
            const short* vtb = vth + (size_t)jn * 4096;
            load_lds16(ktb + (size_t)tid * 8, &kv[bo + wave * 512]);
            load_lds16(vtb + (size_t)tid * 8, &kv[bo + 4096 + wave * 512]);
        }

        // ---- participation test (wave-uniform) ----
        const bool part = (jb <= myqi) &&
                          (((myqi - jb) < 8) || (((jb + h + 1) & 7) == 0));
        if (part) {
            const short* kb = &kv[(t & 1) * 8192];
            const short* vb = kb + 4096;

            // ---- S = Q K^T (C: row=qrow=quad*4+r, col=key=nt*16+l16) ----
            f32x4 s[4];
            #pragma unroll
            for (int nt = 0; nt < 4; ++nt) {
                bf16x8 k0 = *(const bf16x8*)&kb[nt * 1024 + rowb + gk0];
                bf16x8 k1 = *(const bf16x8*)&kb[nt * 1024 + rowb + gk1];
                s[nt] = (f32x4){0.f,0.f,0.f,0.f};
                s[nt] = __builtin_amdgcn_mfma_f32_16x16x32_bf16(a_q[0], k0, s[nt], 0, 0, 0);
                s[nt] = __builtin_amdgcn_mfma_f32_16x16x32_bf16(a_q[1], k1, s[nt], 0, 0, 0);
            }

            // ---- static-max softmax + swizzled P write ----
            const bool diag = (jb == myqi);
            #pragma unroll
            for (int nt = 0; nt < 4; ++nt) {
                const int gw = nt * 2 + (l16 >> 3);   // key group = key>>3
                const int ow = l16 & 7;               // key offset in group
                #pragma unroll
                for (int r = 0; r < 4; ++r) {
                    float raw = s[nt][r];
                    const int mrow = stripe * 16 + quad * 4 + r;
                    if (diag) {
                        int n = nt * 16 + l16;
                        if (n > mrow) raw = -INFINITY;
                    }
                    float pv = __builtin_amdgcn_exp2f(fmaf(raw, kscale, -SMAX));
                    lsum[r] += pv;
                    const int prow = quad * 4 + r;
                    pw[prow * 64 + ((gw ^ (prow & 7)) << 3) + ow] = f2bf_trunc(pv);
                }
            }

            // ---- P A-frags (b128, same swizzle formula) ----
            bf16x8 a_p0 = *(const bf16x8*)&pw[pr0];
            bf16x8 a_p1 = *(const bf16x8*)&pw[pr1];

            // ---- O += P V ----
            #pragma unroll
            for (int nt = 0; nt < 4; ++nt) {
                bf16x8 v0 = *(const bf16x8*)&vb[nt * 1024 + rowb + gk0];
                bf16x8 v1 = *(const bf16x8*)&vb[nt * 1024 + rowb + gk1];
                o[nt] = __builtin_amdgcn_mfma_f32_16x16x32_bf16(a_p0, v0, o[nt], 0, 0, 0);
                o[nt] = __builtin_amdgcn_mfma_f32_16x16x32_bf16(a_p1, v1, o[nt], 0, 0, 0);
            }
        }
    }

    // ---- final l reduction + epilogue ----
    #pragma unroll
    for (int r = 0; r < 4; ++r) {
        float tsum = lsum[r];
        #pragma unroll
        for (int off = 1; off < 16; off <<= 1)
            tsum += __shfl_xor(tsum, off);
        float inv = 1.0f / tsum;
        int trow = row0 + quad * 4 + r;
        float* orow = out + ((size_t)trow * NHEADS + h) * HDIM;
        #pragma unroll
        for (int nt = 0; nt < 4; ++nt)
            orow[nt * 16 + l16] = o[nt][r] * inv;
    }
}

extern "C" void kernel_launch(void* const* d_in, const int* in_sizes, int n_in,
                              void* d_out, int out_size, void* d_ws, size_t ws_size,
                              hipStream_t stream) {
    const float* q = (const float*)d_in[0];
    const float* k = (const float*)d_in[1];
    const float* v = (const float*)d_in[2];
    float* out = (float*)d_out;

    const size_t tileBytes = (size_t)NHEADS * NBLK * 4096 * sizeof(short); // 8 MiB each
    short* kt = (short*)d_ws;
    short* vt = (short*)((char*)d_ws + tileBytes);
    prep_kernel<<<dim3(NHEADS * NBLK), dim3(256), 0, stream>>>(k, v, kt, vt);
    attn_kernel<<<dim3(512), dim3(512), 0, stream>>>(kt, vt, q, out);
}